// Round 3
// baseline (1056.120 us; speedup 1.0000x reference)
//
#include <hip/hip_runtime.h>

#define BB 16384
#define NN 32
#define DD 256
#define CC 128
#define HH 8
#define ALPHA 0.2f
#define GRID 768            // 3 blocks/CU x 256 CUs; blocks grid-stride over nodes

// LDS geometry (bf16 elems)
#define SA_STRIDE 264       // 256 + 8 pad; 528 B row, 16B-aligned
#define SA_BUF    8712      // 33 rows * 264, shorts per staging buffer
#define SP_STRIDE 48        // 32 + 16 pad; 96 B row, 16B-aligned

typedef __attribute__((ext_vector_type(8))) short bf16x8;
typedef __attribute__((ext_vector_type(4))) float f32x4;

// fp32 -> bf16 bits, round-to-nearest-even
__device__ __forceinline__ unsigned short f2b(float x) {
    unsigned int u = __float_as_uint(x);
    return (unsigned short)((u + 0x7fffu + ((u >> 16) & 1u)) >> 16);
}
__device__ __forceinline__ uint2 pack4(float a, float b, float c, float d) {
    uint2 r;
    r.x = (unsigned)f2b(a) | ((unsigned)f2b(b) << 16);
    r.y = (unsigned)f2b(c) | ((unsigned)f2b(d) << 16);
    return r;
}

// ---------------------------------------------------------------------------
// Prep kernel (unchanged): build MFMA B-fragment tables in d_ws.
//  kfrag: kern bf16, frag addr ((nt*8+ks)*64+lane)*8+j
//  sfrag: [Kad | Kas] (256x16) same layout
// ---------------------------------------------------------------------------
__global__ __launch_bounds__(256) void prep_kernel(const float* __restrict__ kern,
                                                   const float* __restrict__ attn,
                                                   unsigned short* __restrict__ kfrag,
                                                   unsigned short* __restrict__ sfrag) {
    if (blockIdx.x < 16) {
        int tid = blockIdx.x * 256 + threadIdx.x;    // 0..4095
        int nt   = tid >> 9;
        int ks   = (tid >> 6) & 7;
        int lane = tid & 63;
        int q    = lane >> 4;
        int cc   = lane & 15;
        int c    = nt * 16 + cc;
        unsigned short v[8];
#pragma unroll
        for (int j = 0; j < 8; ++j) {
            int k = ks * 32 + q * 8 + j;
            v[j] = f2b(kern[k * CC + c]);
        }
        uint4* dst = (uint4*)(kfrag + ((size_t)(nt * 8 + ks) * 64 + lane) * 8);
        uint4 pk;
        pk.x = (unsigned)v[0] | ((unsigned)v[1] << 16);
        pk.y = (unsigned)v[2] | ((unsigned)v[3] << 16);
        pk.z = (unsigned)v[4] | ((unsigned)v[5] << 16);
        pk.w = (unsigned)v[6] | ((unsigned)v[7] << 16);
        *dst = pk;
    } else {
        int sid = (blockIdx.x - 16) * 256 + threadIdx.x;  // 0..511
        int ks   = sid >> 6;
        int lane = sid & 63;
        int q    = lane >> 4;
        int cc   = lane & 15;
        unsigned short v[8];
#pragma unroll
        for (int j = 0; j < 8; ++j) {
            int k = ks * 32 + q * 8 + j;
            const float* krow = kern + (size_t)k * CC;
            const float* arow = (cc < 8) ? (attn + cc * (2 * CC) + CC)
                                         : (attn + (cc - 8) * (2 * CC));
            float s0 = 0.f, s1 = 0.f;
#pragma unroll 4
            for (int c = 0; c < CC; c += 2) {
                s0 += krow[c] * arow[c];
                s1 += krow[c + 1] * arow[c + 1];
            }
            v[j] = f2b(s0 + s1);
        }
        uint4* dst = (uint4*)(sfrag + ((size_t)ks * 64 + lane) * 8);
        uint4 pk;
        pk.x = (unsigned)v[0] | ((unsigned)v[1] << 16);
        pk.y = (unsigned)v[2] | ((unsigned)v[3] << 16);
        pk.z = (unsigned)v[4] | ((unsigned)v[5] << 16);
        pk.w = (unsigned)v[6] | ((unsigned)v[7] << 16);
        *dst = pk;
    }
}

// ---------------------------------------------------------------------------
// Persistent fused kernel: 768 blocks x 256 threads; each block grid-strides
// over nodes with double-buffered register->LDS staging (prefetch node i+1's
// HBM reads while computing node i). kern B-fragments live in registers for
// the whole block (loaded once, not per node).
// LDS: 2x17424 (sA dbuf) + 12288 (sP) + 1024 (cfrag) + 1024 (sDst) + 32 (sSrc)
//    = 49216 B -> 3 blocks/CU.
// ---------------------------------------------------------------------------
__global__ __launch_bounds__(256, 3) void gat_kernel(const float* __restrict__ node,
                                                     const float* __restrict__ neigh,
                                                     const float* __restrict__ bias,
                                                     const unsigned short* __restrict__ kfrag,
                                                     const unsigned short* __restrict__ sfrag,
                                                     float* __restrict__ out) {
    const int t    = threadIdx.x;
    const int lane = t & 63;
    const int wave = t >> 6;
    const int q    = lane >> 4;
    const int m15  = lane & 15;

    __shared__ __align__(16) char smem[49216];
    unsigned short* sAb   = (unsigned short*)smem;            // 2 x 17424 B
    unsigned short* sP    = (unsigned short*)(smem + 34848);  // 12288 B
    unsigned short* cfrag = (unsigned short*)(smem + 47136);  // 1024 B
    float*          sDst  = (float*)(smem + 48160);           // 1024 B
    float*          sSrc  = (float*)(smem + 49184);           // 32 B

    // ---- Hoist kern B-fragments into registers (reused for every node) ----
    bf16x8 kb[2][8];
#pragma unroll
    for (int i = 0; i < 2; ++i)
#pragma unroll
        for (int ks = 0; ks < 8; ++ks)
            kb[i][ks] = *(const bf16x8*)(kfrag + ((size_t)((wave * 2 + i) * 8 + ks) * 64 + lane) * 8);

    const float4* nb4 = (const float4*)neigh;
    const float4* nd4 = (const float4*)node;

    float4 st[9];   // staged fp32 rows for next node (33*64 float4 / 256 thr)

#define LOAD_NODE(bb)                                                          \
    {                                                                          \
        _Pragma("unroll")                                                      \
        for (int k = 0; k < 9; ++k) {                                          \
            int j = k * 256 + t;                                               \
            if (j < 33 * 64) {                                                 \
                int row = j >> 6, d4 = j & 63;                                 \
                st[k] = (row < 32) ? nb4[(size_t)(bb) * 2048 + row * 64 + d4]  \
                                   : nd4[(size_t)(bb) * 64 + d4];              \
            }                                                                  \
        }                                                                      \
    }

#define WRITE_NODE(buf)                                                        \
    {                                                                          \
        unsigned short* sAw = sAb + (buf) * SA_BUF;                            \
        _Pragma("unroll")                                                      \
        for (int k = 0; k < 9; ++k) {                                          \
            int j = k * 256 + t;                                               \
            if (j < 33 * 64) {                                                 \
                int row = j >> 6, d4 = j & 63;                                 \
                *(uint2*)(sAw + row * SA_STRIDE + d4 * 4) =                    \
                    pack4(st[k].x, st[k].y, st[k].z, st[k].w);                 \
            }                                                                  \
        }                                                                      \
    }

    int b = blockIdx.x;
    LOAD_NODE(b);
    WRITE_NODE(0);
    __syncthreads();
    int cur = 0;

    while (true) {
        const int  bn   = b + GRID;
        const bool more = (bn < BB);
        if (more) LOAD_NODE(bn);          // prefetch next node's HBM reads

        const unsigned short* sA = sAb + cur * SA_BUF;

        // ---- Phase 3: scores via MFMA. waves 0..2 take M-tile = wave ----
        if (wave < 3) {
            f32x4 acc = {0.f, 0.f, 0.f, 0.f};
            const unsigned short* abase = sA + (wave * 16 + m15) * SA_STRIDE + q * 8;
#pragma unroll
            for (int ks = 0; ks < 8; ++ks) {
                bf16x8 bfr = *(const bf16x8*)(sfrag + ((size_t)ks * 64 + lane) * 8);
                bf16x8 afr = *(const bf16x8*)(abase + ks * 32);
                acc = __builtin_amdgcn_mfma_f32_16x16x32_bf16(afr, bfr, acc, 0, 0, 0);
            }
#pragma unroll
            for (int r = 0; r < 4; ++r) {
                int row = wave * 16 + q * 4 + r;
                if (row < 32 && m15 < 8) sDst[row * 8 + m15] = acc[r];
                if (row == 32 && m15 >= 8) sSrc[m15 - 8] = acc[r];
            }
        }

        // ---- Phase 1: neigh_p via MFMA; A-frags loaded once per mt, reused ----
#pragma unroll
        for (int mt = 0; mt < 2; ++mt) {
            bf16x8 afr[8];
            const unsigned short* abase = sA + (mt * 16 + m15) * SA_STRIDE + q * 8;
#pragma unroll
            for (int ks = 0; ks < 8; ++ks)
                afr[ks] = *(const bf16x8*)(abase + ks * 32);
#pragma unroll
            for (int i = 0; i < 2; ++i) {
                f32x4 acc = {0.f, 0.f, 0.f, 0.f};
#pragma unroll
                for (int ks = 0; ks < 8; ++ks)
                    acc = __builtin_amdgcn_mfma_f32_16x16x32_bf16(afr[ks], kb[i][ks], acc, 0, 0, 0);
                // transpose-store: col c fixed per lane, 4 consecutive n
                int c  = (wave * 2 + i) * 16 + m15;
                int n0 = mt * 16 + q * 4;
                *(uint2*)(sP + c * SP_STRIDE + n0) = pack4(acc[0], acc[1], acc[2], acc[3]);
            }
        }
        __syncthreads();

        // ---- Phase 4: softmax over n (fp32). thread t -> h = t>>5, n = t&31 ----
        {
            int h = t >> 5, n = t & 31;
            float sc = sSrc[h] + sDst[n * 8 + h];
            sc = fmaxf(sc, ALPHA * sc);              // leaky relu
            float m = sc;
#pragma unroll
            for (int off = 16; off >= 1; off >>= 1) m = fmaxf(m, __shfl_xor(m, off, 32));
            float e = expf(sc - m);
            float den = e;
#pragma unroll
            for (int off = 16; off >= 1; off >>= 1) den += __shfl_xor(den, off, 32);
            float coef = e / den;
            int l1 = (n >> 3) * 16 + h;              // cols 0..7: coef
            int jj = n & 7;
            cfrag[l1 * 8 + jj] = f2b(coef);
            cfrag[(l1 + 8) * 8 + jj] = 0;            // cols 8..15: zero
        }
        __syncthreads();

        // ---- Phase 5: z^T = sP^T @ coef. wave handles M-tiles {2w, 2w+1} ----
        {
            bf16x8 cb = *(const bf16x8*)(cfrag + (size_t)lane * 8);
            f32x4 zero = {0.f, 0.f, 0.f, 0.f};
#pragma unroll
            for (int i = 0; i < 2; ++i) {
                int mt5 = wave * 2 + i;
                bf16x8 afr = *(const bf16x8*)(sP + (mt5 * 16 + m15) * SP_STRIDE + q * 8);
                f32x4 acc = __builtin_amdgcn_mfma_f32_16x16x32_bf16(afr, cb, zero, 0, 0, 0);
                if (m15 < 8) {                        // col = h; cols 8..15 zero-pad
                    int h  = m15;
                    int c0 = mt5 * 16 + q * 4;
                    float4 bv = *(const float4*)(bias + h * CC + c0);
                    float4 r;
                    r.x = acc[0] + bv.x;
                    r.y = acc[1] + bv.y;
                    r.z = acc[2] + bv.z;
                    r.w = acc[3] + bv.w;
                    *(float4*)(out + (size_t)b * (HH * CC) + h * CC + c0) = r;
                }
            }
        }

        if (!more) break;
        WRITE_NODE(cur ^ 1);   // drain prefetch into the other buffer
        __syncthreads();
        cur ^= 1;
        b = bn;
    }
#undef LOAD_NODE
#undef WRITE_NODE
}

extern "C" void kernel_launch(void* const* d_in, const int* in_sizes, int n_in,
                              void* d_out, int out_size, void* d_ws, size_t ws_size,
                              hipStream_t stream) {
    const float* node  = (const float*)d_in[0];   // (B, D)
    const float* neigh = (const float*)d_in[1];   // (B, N, D)
    const float* kern  = (const float*)d_in[2];   // (D, C)
    const float* attn  = (const float*)d_in[3];   // (1, H, 2C)
    const float* bias  = (const float*)d_in[4];   // (H*C,)
    float* out = (float*)d_out;                   // (1, B, H*C)

    unsigned short* kfrag = (unsigned short*)d_ws;                  // 65536 B
    unsigned short* sfrag = (unsigned short*)((char*)d_ws + 65536); // 8192 B

    hipLaunchKernelGGL(prep_kernel, dim3(18), dim3(256), 0, stream, kern, attn, kfrag, sfrag);
    hipLaunchKernelGGL(gat_kernel, dim3(GRID), dim3(256), 0, stream,
                       node, neigh, bias, kfrag, sfrag, out);
}